// Round 2
// baseline (554.682 us; speedup 1.0000x reference)
//
#include <hip/hip_runtime.h>
#include <hip/hip_bf16.h>
#include <stdint.h>

// AdaLoRALinear: out = x @ (W + 2*(P*Lambda*mask)@Q)^T
//  = x@W^T + 2*(x@Q^T)@(P*Lambda*mask)^T
// Decomposition: U = Xb@Qb^T [8192x64], V = 2*lam*mask*P [4096x64];
// main gemm does C = Xb@Wb^T then one extra rank-64 K-tile from U,V.
#define M_TOK 8192   // batch tokens
#define NF    4096   // OUT_F
#define KF    4096   // IN_F
#define RANK  64

typedef __attribute__((ext_vector_type(8))) short short8;   // 8 x bf16 (4 VGPRs)
typedef __attribute__((ext_vector_type(4))) float floatx4;  // MFMA acc

typedef const uint32_t __attribute__((address_space(1)))* gp1_t;
typedef uint32_t __attribute__((address_space(3)))* lp3_t;

__device__ __forceinline__ void load_lds16(const void* g, void* l) {
  // async global->LDS, 16 B per lane; LDS dest must be uniform_base + lane*16
  __builtin_amdgcn_global_load_lds((gp1_t)g, (lp3_t)l, 16, 0, 0);
}

// ---------------- Kernel 1: fp32 -> bf16 cast, 8 elems/thread ----------------
// (used for both x->Xb and weight->Wb)
__global__ void cast_f32_bf16(const float* __restrict__ in,
                              __hip_bfloat16* __restrict__ out) {
  size_t i = ((size_t)blockIdx.x * blockDim.x + threadIdx.x) * 8;
  float4 a = *(const float4*)(in + i);
  float4 b = *(const float4*)(in + i + 4);
  union { __hip_bfloat16 h[8]; uint4 u; } pk;
  pk.h[0] = __float2bfloat16(a.x);
  pk.h[1] = __float2bfloat16(a.y);
  pk.h[2] = __float2bfloat16(a.z);
  pk.h[3] = __float2bfloat16(a.w);
  pk.h[4] = __float2bfloat16(b.x);
  pk.h[5] = __float2bfloat16(b.y);
  pk.h[6] = __float2bfloat16(b.z);
  pk.h[7] = __float2bfloat16(b.w);
  *(uint4*)(out + i) = pk.u;
}

// ---- Kernel 2: Qb = bf16(Q) [64][4096]; Vb = bf16(2*Lam*mask*P) [4096][64].
// 256 blocks x 256 thr; blocks 0-127 handle Q (32768*8 elems), 128-255 handle P.
__global__ __launch_bounds__(256) void prep_qv(
    const float* __restrict__ Q, const float* __restrict__ P,
    const float* __restrict__ Lam, const unsigned char* __restrict__ mask,
    __hip_bfloat16* __restrict__ Qb, __hip_bfloat16* __restrict__ Vb) {
  int idx = blockIdx.x * 256 + threadIdx.x;
  if (idx < (RANK * KF) / 8) {
    size_t i = (size_t)idx * 8;
    float4 a = *(const float4*)(Q + i);
    float4 b = *(const float4*)(Q + i + 4);
    union { __hip_bfloat16 h[8]; uint4 u; } pk;
    pk.h[0] = __float2bfloat16(a.x); pk.h[1] = __float2bfloat16(a.y);
    pk.h[2] = __float2bfloat16(a.z); pk.h[3] = __float2bfloat16(a.w);
    pk.h[4] = __float2bfloat16(b.x); pk.h[5] = __float2bfloat16(b.y);
    pk.h[6] = __float2bfloat16(b.z); pk.h[7] = __float2bfloat16(b.w);
    *(uint4*)(Qb + i) = pk.u;
  } else {
    idx -= (RANK * KF) / 8;
    size_t i = (size_t)idx * 8;            // flat index into P [4096][64]
    const int rb = (int)(i & (RANK - 1));  // rank offset, multiple of 8
    float4 a = *(const float4*)(P + i);
    float4 b = *(const float4*)(P + i + 4);
    float s[8];
#pragma unroll
    for (int j = 0; j < 8; ++j)
      s[j] = 2.0f * Lam[rb + j] * (mask[rb + j] ? 1.0f : 0.0f);
    union { __hip_bfloat16 h[8]; uint4 u; } pk;
    pk.h[0] = __float2bfloat16(a.x * s[0]); pk.h[1] = __float2bfloat16(a.y * s[1]);
    pk.h[2] = __float2bfloat16(a.z * s[2]); pk.h[3] = __float2bfloat16(a.w * s[3]);
    pk.h[4] = __float2bfloat16(b.x * s[4]); pk.h[5] = __float2bfloat16(b.y * s[5]);
    pk.h[6] = __float2bfloat16(b.z * s[6]); pk.h[7] = __float2bfloat16(b.w * s[7]);
    *(uint4*)(Vb + i) = pk.u;
  }
}

// ---- Kernel 3: U[m][r] = sum_k Xb[m][k]*Qb[r][k], bf16 out.
// 256 blocks x 128 thr (2 waves); wave owns 16 m-rows x 64 rank-cols.
// No LDS: A-frags stream from global, Qb (512 KB) is L2-hot.
__global__ __launch_bounds__(128) void gemm_xqt(
    const __hip_bfloat16* __restrict__ X,   // [M_TOK][KF]
    const __hip_bfloat16* __restrict__ Qb,  // [RANK][KF]
    __hip_bfloat16* __restrict__ U) {       // [M_TOK][RANK]
  const int t = threadIdx.x;
  const int lane = t & 63;
  const int w = t >> 6;
  const int frow = lane & 15;
  const int kq = lane >> 4;
  const int m0 = blockIdx.x * 32 + w * 16;
  const __hip_bfloat16* xp = X + (size_t)(m0 + frow) * KF + kq * 8;
  floatx4 acc[4] = {};
#pragma unroll 4
  for (int k0 = 0; k0 < KF; k0 += 32) {
    short8 af = *(const short8*)(xp + k0);
#pragma unroll
    for (int nf = 0; nf < 4; ++nf) {
      short8 bf = *(const short8*)(Qb + (size_t)(nf * 16 + frow) * KF + k0 + kq * 8);
      acc[nf] = __builtin_amdgcn_mfma_f32_16x16x32_bf16(af, bf, acc[nf], 0, 0, 0);
    }
  }
  // D layout: col(n)=lane&15, row(m)=(lane>>4)*4+reg
  const int col = lane & 15;
  const int r0 = (lane >> 4) * 4;
#pragma unroll
  for (int nf = 0; nf < 4; ++nf)
#pragma unroll
    for (int r = 0; r < 4; ++r)
      U[(size_t)(m0 + r0 + r) * RANK + nf * 16 + col] =
          __float2bfloat16(acc[nf][r]);
}

// ---- Kernel 4: C[m][n] = sum_k A[m][k]*B[n][k] + sum_r U[m][r]*V[n][r].
//
// 256x256 tile, BK=64, 512 threads (8 waves, 2Mx4N), per-wave 128x64 output.
// 4 phases/K-tile; NEW this round: register-subtile double-buffering with
// COUNTED lgkmcnt — each phase issues the NEXT subtile's ds_reads before its
// own MFMA cluster and waits lgkmcnt(4) (only the previous issue group), so
// the LDS pipe drains during MFMA windows instead of alternating with them.
// 2-K-tile unrolled loop for static frag/slot indexing (rule #20):
//   bE/bO = B frags (even/odd tile), aX/aY = A-quad ping-pong (subtile s -> s&1).
// vmcnt(2) moved to phase 2 (retires A(t+1),B(t+1)) so phase 3 can legally
// pre-read next tile's subtile 0 (B-next 8 + Aq0 4 = 12 reads, lgkmcnt(12)).
// Per-wave lgkm ledger (pure-DS in flight -> in-order retirement):
//   ph0: +4 -> 16, wait(4)  retires B+Aq0 of cur tile
//   ph1: +4 ->  8, wait(4)  retires Aq1
//   ph2: +4 ->  8, wait(4)  retires Aq2 ; then vmcnt(2)+barrier
//   ph3: +12-> 16, wait(12) retires Aq3
// Race windows (all >=1 barrier separated, as before):
//   B-reads of tile t retire at ph0's wait (before ph0 post-MFMA barrier);
//   STAGE_B(t+2,cur) issues ph2 — safe. A WAR guarded by end-of-tile barrier.
//   ph3's next-slot reads follow ph2's vmcnt(2)+barrier (data landed).
#define BM 256
#define BN 256
#define BK 64
#define NT (KF / BK)   // 64
#define ASL 16384      // elements per K-tile slot (256*64)

#define SB0 __builtin_amdgcn_sched_barrier(0)
#define BARSYNC do { SB0; __builtin_amdgcn_s_barrier(); } while (0)
#define LGK(n) do { asm volatile("s_waitcnt lgkmcnt(" #n ")" ::: "memory"); SB0; } while (0)

__device__ __forceinline__ void read_a4(short8 (&afr)[2][2],
                                        const __hip_bfloat16* Asl,
                                        int row_base, int swz) {
#pragma unroll
  for (int mm = 0; mm < 2; ++mm)
#pragma unroll
    for (int ks = 0; ks < 2; ++ks)
      afr[mm][ks] = *(const short8*)(Asl + ks * 8192 + (row_base + mm * 16) * 32 + swz);
}

__device__ __forceinline__ void read_b8(short8 (&bfr)[4][2],
                                        const __hip_bfloat16* Bsl,
                                        int brow, int swz) {
#pragma unroll
  for (int nf = 0; nf < 4; ++nf)
#pragma unroll
    for (int ks = 0; ks < 2; ++ks)
      bfr[nf][ks] = *(const short8*)(Bsl + ks * 8192 + (brow + nf * 16) * 32 + swz);
}

template <int P>
__device__ __forceinline__ void mfma16(floatx4 (&acc)[8][4],
                                       const short8 (&afr)[2][2],
                                       const short8 (&bfr)[4][2]) {
#pragma unroll
  for (int ks = 0; ks < 2; ++ks)
#pragma unroll
    for (int mm = 0; mm < 2; ++mm)
#pragma unroll
      for (int nf = 0; nf < 4; ++nf)
        acc[P * 2 + mm][nf] = __builtin_amdgcn_mfma_f32_16x16x32_bf16(
            afr[mm][ks], bfr[nf][ks], acc[P * 2 + mm][nf], 0, 0, 0);
}

__global__ __launch_bounds__(512, 2) void gemm_xwt(
    const __hip_bfloat16* __restrict__ A,   // [M_TOK][KF]
    const __hip_bfloat16* __restrict__ B,   // [NF][KF]  (= Wb, row = n)
    const __hip_bfloat16* __restrict__ U,   // [M_TOK][RANK]
    const __hip_bfloat16* __restrict__ V,   // [NF][RANK]
    float* __restrict__ C) {                // [M_TOK][NF]
  extern __shared__ __hip_bfloat16 lds[];
  __hip_bfloat16* As = lds;            // 2 slots x 16384 elems
  __hip_bfloat16* Bs = lds + 2 * ASL;  // 2 slots x 16384 elems
  const __hip_bfloat16* As0 = As;
  const __hip_bfloat16* As1 = As + ASL;
  const __hip_bfloat16* Bs0 = Bs;
  const __hip_bfloat16* Bs1 = Bs + ASL;

  const int t = threadIdx.x;       // 0..511
  const int lane = t & 63;
  const int wave = t >> 6;         // 0..7
  const int wm = wave >> 2;        // 0..1 : M half (128 rows)
  const int wn = wave & 3;         // 0..3 : N quarter (64 cols)
  const int frow = lane & 15;
  const int kq = lane >> 4;
  const int swz = ((kq + (frow >> 1)) & 3) * 8;   // swizzled k-elem offset

  // XCD-bijective block swizzle: 512 wgs, 8 XCDs, 64 contiguous work/XCD.
  const int bid = blockIdx.x;
  const int wk = (bid & 7) * 64 + (bid >> 3);
  const int bm = wk >> 4;   // 0..31
  const int bn = wk & 15;   // 0..15

  // staging: thread t covers within-panel row (t>>2)(+h*128), global chunk c
  const int c = ((t & 3) - ((t >> 3) & 3)) & 3;
  const __hip_bfloat16* a_src = A + (size_t)(bm * BM + (t >> 2)) * KF + c * 8;
  const __hip_bfloat16* b_src = B + (size_t)(bn * BN + (t >> 2)) * KF + c * 8;
  __hip_bfloat16* a_dst = As + t * 8;
  __hip_bfloat16* b_dst = Bs + t * 8;

#define STAGE_A(kt_, slot_, h_)                                                        \
  do {                                                                                 \
    const __hip_bfloat16* s_ = a_src + ((kt_) & (NT - 1)) * BK + (size_t)(h_) * 128 * KF; \
    __hip_bfloat16* d_ = a_dst + (slot_) * ASL + (h_) * 4096;                          \
    load_lds16(s_, d_);                /* ks=0 panel */                                \
    load_lds16(s_ + 32, d_ + 8192);    /* ks=1 panel */                                \
  } while (0)
#define STAGE_B(kt_, slot_, h_)                                                        \
  do {                                                                                 \
    const __hip_bfloat16* s_ = b_src + ((kt_) & (NT - 1)) * BK + (size_t)(h_) * 128 * KF; \
    __hip_bfloat16* d_ = b_dst + (slot_) * ASL + (h_) * 4096;                          \
    load_lds16(s_, d_);                                                                \
    load_lds16(s_ + 32, d_ + 8192);                                                    \
  } while (0)

  floatx4 acc[8][4] = {};
  short8 bE[4][2], bO[4][2];   // B frags, even/odd tile
  short8 aX[2][2], aY[2][2];   // A-quad ping-pong

  const int arow = wm * 128 + frow;
  const int brow = wn * 64 + frow;

  // prologue: A(0),B(0) must land; B(1) may fly.
  STAGE_A(0, 0, 0); STAGE_A(0, 0, 1);
  STAGE_B(0, 0, 0); STAGE_B(0, 0, 1);
  STAGE_B(1, 1, 0); STAGE_B(1, 1, 1);
  asm volatile("s_waitcnt vmcnt(4)" ::: "memory");
  __builtin_amdgcn_s_barrier();
  read_b8(bE, Bs0, brow, swz);              // 8 reads  (tile 0 B)
  read_a4(aX, As0, arow + 0 * 32, swz);     // 4 reads  (tile 0 Aq0) -> 12 out

  for (int kt = 0; kt < NT; kt += 2) {
    // ================= tile e = kt (slot 0) =================
    // ph0
    read_a4(aY, As0, arow + 1 * 32, swz);
    STAGE_A(kt + 1, 1, 0);
    BARSYNC; LGK(4);
    __builtin_amdgcn_s_setprio(1); mfma16<0>(acc, aX, bE); __builtin_amdgcn_s_setprio(0);
    BARSYNC;
    // ph1
    read_a4(aX, As0, arow + 2 * 32, swz);
    STAGE_A(kt + 1, 1, 1);
    BARSYNC; LGK(4);
    __builtin_amdgcn_s_setprio(1); mfma16<1>(acc, aY, bE); __builtin_amdgcn_s_setprio(0);
    BARSYNC;
    // ph2  (vmcnt(2): retire A(e+1),B(e+1); keep B(e+2)h0 flying)
    read_a4(aY, As0, arow + 3 * 32, swz);
    STAGE_B(kt + 2, 0, 0);
    BARSYNC; LGK(4);
    __builtin_amdgcn_s_setprio(1); mfma16<2>(acc, aX, bE); __builtin_amdgcn_s_setprio(0);
    SB0;
    asm volatile("s_waitcnt vmcnt(2)" ::: "memory");
    __builtin_amdgcn_s_barrier();
    // ph3  (pre-read next tile's subtile 0 from slot 1: landed above)
    read_b8(bO, Bs1, brow, swz);
    read_a4(aX, As1, arow + 0 * 32, swz);
    STAGE_B(kt + 2, 0, 1);
    BARSYNC; LGK(12);
    __builtin_amdgcn_s_setprio(1); mfma16<3>(acc, aY, bE); __builtin_amdgcn_s_setprio(0);
    BARSYNC;

    // ================= tile o = kt+1 (slot 1) =================
    // ph0
    read_a4(aY, As1, arow + 1 * 32, swz);
    STAGE_A(kt + 2, 0, 0);
    BARSYNC; LGK(4);
    __builtin_amdgcn_s_setprio(1); mfma16<0>(acc, aX, bO); __builtin_amdgcn_s_setprio(0);
    BARSYNC;
    // ph1
    read_a4(aX, As1, arow + 2 * 32, swz);
    STAGE_A(kt + 2, 0, 1);
    BARSYNC; LGK(4);
    __builtin_amdgcn_s_setprio(1); mfma16<1>(acc, aY, bO); __builtin_amdgcn_s_setprio(0);
    BARSYNC;
    // ph2
    read_a4(aY, As1, arow + 3 * 32, swz);
    STAGE_B(kt + 3, 1, 0);
    BARSYNC; LGK(4);
    __builtin_amdgcn_s_setprio(1); mfma16<2>(acc, aX, bO); __builtin_amdgcn_s_setprio(0);
    SB0;
    asm volatile("s_waitcnt vmcnt(2)" ::: "memory");
    __builtin_amdgcn_s_barrier();
    // ph3
    read_b8(bE, Bs0, brow, swz);
    read_a4(aX, As0, arow + 0 * 32, swz);
    STAGE_B(kt + 3, 1, 1);
    BARSYNC; LGK(12);
    __builtin_amdgcn_s_setprio(1); mfma16<3>(acc, aY, bO); __builtin_amdgcn_s_setprio(0);
    BARSYNC;
  }

#undef STAGE_A
#undef STAGE_B

  // ---- rank-64 epilogue: one extra K-tile from U,V (direct global, L2-hot;
  //      frag layout identical to the LDS path: lane(frow,kq) -> [row][ks*32+kq*8..+7])
  {
    short8 vf[4][2];
#pragma unroll
    for (int nf = 0; nf < 4; ++nf)
#pragma unroll
      for (int ks = 0; ks < 2; ++ks)
        vf[nf][ks] = *(const short8*)(V + (size_t)(bn * BN + wn * 64 + nf * 16 + frow) * RANK + ks * 32 + kq * 8);
#pragma unroll
    for (int p = 0; p < 4; ++p) {
      short8 uf[2][2];
#pragma unroll
      for (int mm = 0; mm < 2; ++mm)
#pragma unroll
        for (int ks = 0; ks < 2; ++ks)
          uf[mm][ks] = *(const short8*)(U + (size_t)(bm * BM + wm * 128 + p * 32 + mm * 16 + frow) * RANK + ks * 32 + kq * 8);
#pragma unroll
      for (int ks = 0; ks < 2; ++ks)
#pragma unroll
        for (int mm = 0; mm < 2; ++mm)
#pragma unroll
          for (int nf = 0; nf < 4; ++nf)
            acc[p * 2 + mm][nf] = __builtin_amdgcn_mfma_f32_16x16x32_bf16(
                uf[mm][ks], vf[nf][ks], acc[p * 2 + mm][nf], 0, 0, 0);
    }
  }

  // epilogue: D mapping col(n)=lane&15, row(m)=(lane>>4)*4+reg  [m89-verified]
  const int col0 = bn * BN + wn * 64 + (lane & 15);
  const int row0 = bm * BM + wm * 128 + (lane >> 4) * 4;
#pragma unroll
  for (int mf = 0; mf < 8; ++mf)
#pragma unroll
    for (int nf = 0; nf < 4; ++nf)
#pragma unroll
      for (int r = 0; r < 4; ++r)
        C[(size_t)(row0 + mf * 16 + r) * NF + (col0 + nf * 16)] = acc[mf][nf][r];
}

extern "C" void kernel_launch(void* const* d_in, const int* in_sizes, int n_in,
                              void* d_out, int out_size, void* d_ws, size_t ws_size,
                              hipStream_t stream) {
  const float* x      = (const float*)d_in[0];  // [8192][4096]
  const float* weight = (const float*)d_in[1];  // [4096][4096]
  const float* P      = (const float*)d_in[2];  // [4096][64]
  const float* Lam    = (const float*)d_in[3];  // [64]
  const float* Q      = (const float*)d_in[4];  // [64][4096]
  const unsigned char* mask = (const unsigned char*)d_in[5];  // [64] bool8
  float* out = (float*)d_out;

  char* ws = (char*)d_ws;
  __hip_bfloat16* Xb = (__hip_bfloat16*)ws;                                  // 64 MB
  __hip_bfloat16* Wb = (__hip_bfloat16*)(ws + (size_t)M_TOK * KF * 2);       // 32 MB @64M
  __hip_bfloat16* Qb = (__hip_bfloat16*)(ws + 96ull * 1024 * 1024);          // 0.5 MB
  __hip_bfloat16* Vb = (__hip_bfloat16*)(ws + 96ull * 1024 * 1024 + (size_t)RANK * KF * 2);  // 0.5 MB
  __hip_bfloat16* Ub = (__hip_bfloat16*)(ws + 97ull * 1024 * 1024);          // 1 MB

  static int smem_set = 0;
  if (!smem_set) {
    hipFuncSetAttribute((const void*)gemm_xwt,
                        hipFuncAttributeMaxDynamicSharedMemorySize, 131072);
    smem_set = 1;
  }

  // 1) x -> bf16
  cast_f32_bf16<<<(M_TOK * KF) / (256 * 8), 256, 0, stream>>>(x, Xb);
  // 2) W -> bf16 (plain cast; rank update moved into gemm epilogue)
  cast_f32_bf16<<<(NF * KF) / (256 * 8), 256, 0, stream>>>(weight, Wb);
  // 3) Qb, Vb
  prep_qv<<<256, 256, 0, stream>>>(Q, P, Lam, mask, Qb, Vb);
  // 4) U = Xb @ Qb^T
  gemm_xqt<<<M_TOK / 32, 128, 0, stream>>>(Xb, Qb, Ub);
  // 5) out = Xb @ Wb^T + U @ Vb^T   (512 blocks = 32 bm x 16 bn, XCD-swizzled)
  gemm_xwt<<<dim3((M_TOK / BM) * (NF / BN)), 512, 131072, stream>>>(Xb, Wb, Ub, Vb, out);
}

// Round 4
// 531.756 us; speedup vs baseline: 1.0431x; 1.0431x over previous
//
#include <hip/hip_runtime.h>
#include <hip/hip_bf16.h>
#include <stdint.h>

// Problem constants (AdaLoRALinear): out = x @ (W + 2*(P*Lambda*mask)@Q)^T
// Pipeline (all components individually harness-proven):
//   1) cast_f32_bf16 : x -> Xb (bf16)                [round 0/1/2, passing]
//   2) build_weff    : Wb = bf16(W + 2*(P*lam*mask)@Q)  [round 0/1, passing]
//   3) gemm_xwt      : out = Xb @ Wb^T  — round-2 loop (243.7 us, MfmaUtil 51.4,
//                      0 bank conflicts) with the rank-64 U/V epilogue DELETED
//                      (not needed on the build_weff path).
#define M_TOK 8192   // batch tokens
#define NF    4096   // OUT_F
#define KF    4096   // IN_F
#define RANK  64

typedef __attribute__((ext_vector_type(8))) short short8;   // 8 x bf16 (4 VGPRs)
typedef __attribute__((ext_vector_type(4))) float floatx4;  // MFMA acc

typedef const uint32_t __attribute__((address_space(1)))* gp1_t;
typedef uint32_t __attribute__((address_space(3)))* lp3_t;

__device__ __forceinline__ void load_lds16(const void* g, void* l) {
  // async global->LDS, 16 B per lane; LDS dest must be uniform_base + lane*16
  __builtin_amdgcn_global_load_lds((gp1_t)g, (lp3_t)l, 16, 0, 0);
}

// ---------------- Kernel 1: x (fp32) -> bf16, 8 elems/thread ----------------
__global__ void cast_f32_bf16(const float* __restrict__ in,
                              __hip_bfloat16* __restrict__ out) {
  size_t i = ((size_t)blockIdx.x * blockDim.x + threadIdx.x) * 8;
  float4 a = *(const float4*)(in + i);
  float4 b = *(const float4*)(in + i + 4);
  union { __hip_bfloat16 h[8]; uint4 u; } pk;
  pk.h[0] = __float2bfloat16(a.x);
  pk.h[1] = __float2bfloat16(a.y);
  pk.h[2] = __float2bfloat16(a.z);
  pk.h[3] = __float2bfloat16(a.w);
  pk.h[4] = __float2bfloat16(b.x);
  pk.h[5] = __float2bfloat16(b.y);
  pk.h[6] = __float2bfloat16(b.z);
  pk.h[7] = __float2bfloat16(b.w);
  *(uint4*)(out + i) = pk.u;
}

// ---- Kernel 2: W_eff[n][k] = W[n][k] + 2*sum_r P[n][r]*Lam[r]*mask[r]*Q[r][k],
//      cast to bf16. Tile 64n x 64k per block, 256 threads, rank staged in LDS.
__global__ __launch_bounds__(256) void build_weff(
    const float* __restrict__ W, const float* __restrict__ P,
    const float* __restrict__ Lam, const float* __restrict__ Q,
    const unsigned char* __restrict__ mask,   // jnp.bool_ -> 1 byte/elem
    __hip_bfloat16* __restrict__ Wb) {
  __shared__ float lam[RANK];
  __shared__ float plT[RANK][68];  // [r][n_local], padded vs bank conflicts
  __shared__ float Qs[RANK][68];   // [r][k_local]

  const int t = threadIdx.x;
  const int n0 = blockIdx.y * 64;
  const int k0 = blockIdx.x * 64;

  if (t < RANK) lam[t] = 2.0f * Lam[t] * (mask[t] ? 1.0f : 0.0f);
  __syncthreads();

  {
    // stage P^T * lam : thread t covers n_local = t&63, r-range (t>>6)*16..+15
    const int nl = t & 63;
    const int rg = (t >> 6) * 16;
    const float* p = P + (size_t)(n0 + nl) * RANK + rg;
#pragma unroll
    for (int j = 0; j < 16; j += 4) {
      float4 v = *(const float4*)(p + j);
      plT[rg + j + 0][nl] = v.x * lam[rg + j + 0];
      plT[rg + j + 1][nl] = v.y * lam[rg + j + 1];
      plT[rg + j + 2][nl] = v.z * lam[rg + j + 2];
      plT[rg + j + 3][nl] = v.w * lam[rg + j + 3];
    }
    // stage Q tile: thread t covers r = t>>2, k-range (t&3)*16..+15
    const int r = t >> 2;
    const int kc = (t & 3) * 16;
    const float* q = Q + (size_t)r * KF + k0 + kc;
#pragma unroll
    for (int j = 0; j < 16; j += 4) {
      float4 v = *(const float4*)(q + j);
      Qs[r][kc + j + 0] = v.x;
      Qs[r][kc + j + 1] = v.y;
      Qs[r][kc + j + 2] = v.z;
      Qs[r][kc + j + 3] = v.w;
    }
  }
  __syncthreads();

  const int tn4 = t >> 4;  // 0..15 -> n-group of 4
  const int tk4 = t & 15;  // 0..15 -> k-group of 4
  float accv[4][4];
#pragma unroll
  for (int i = 0; i < 4; i++) {
    float4 w = *(const float4*)(W + (size_t)(n0 + tn4 * 4 + i) * KF + k0 + tk4 * 4);
    accv[i][0] = w.x; accv[i][1] = w.y; accv[i][2] = w.z; accv[i][3] = w.w;
  }
#pragma unroll 8
  for (int r = 0; r < RANK; r++) {
    float4 p4 = *(const float4*)&plT[r][tn4 * 4];
    float4 q4 = *(const float4*)&Qs[r][tk4 * 4];
#define ROWFMA(i, pi)                                                  \
    accv[i][0] += (pi) * q4.x; accv[i][1] += (pi) * q4.y;              \
    accv[i][2] += (pi) * q4.z; accv[i][3] += (pi) * q4.w;
    ROWFMA(0, p4.x) ROWFMA(1, p4.y) ROWFMA(2, p4.z) ROWFMA(3, p4.w)
#undef ROWFMA
  }
#pragma unroll
  for (int i = 0; i < 4; i++) {
    union { __hip_bfloat16 h[4]; uint2 u; } pk;
    pk.h[0] = __float2bfloat16(accv[i][0]);
    pk.h[1] = __float2bfloat16(accv[i][1]);
    pk.h[2] = __float2bfloat16(accv[i][2]);
    pk.h[3] = __float2bfloat16(accv[i][3]);
    *(uint2*)(Wb + (size_t)(n0 + tn4 * 4 + i) * KF + k0 + tk4 * 4) = pk.u;
  }
}

// ---- Kernel 3: C[m][n] = sum_k A[m][k]*B[n][k]; A,B bf16 row-major, C fp32.
//
// 256x256 tile, BK=64, 512 threads (8 waves, 2Mx4N), per-wave 128x64 output.
// 4 phases/K-tile with register-subtile double-buffering and COUNTED lgkmcnt:
// each phase issues the NEXT subtile's ds_reads before its own MFMA cluster
// and waits lgkmcnt(4) (only the previous issue group), so the LDS pipe drains
// during MFMA windows. 2-K-tile unrolled loop for static frag/slot indexing.
// vmcnt(2) at phase 2 retires A(t+1),B(t+1) so phase 3 can pre-read next
// tile's subtile 0 (B-next 8 + Aq0 4 = 12 reads, lgkmcnt(12)).
// Per-wave lgkm ledger (pure-DS in flight -> in-order retirement):
//   ph0: +4 -> 16, wait(4)  retires B+Aq0 of cur tile
//   ph1: +4 ->  8, wait(4)  retires Aq1
//   ph2: +4 ->  8, wait(4)  retires Aq2 ; then vmcnt(2)+barrier
//   ph3: +12-> 16, wait(12) retires Aq3
// Race windows all >=1 barrier separated (audited rounds 1-3; ran passing
// in rounds 1 and 2).
#define BM 256
#define BN 256
#define BK 64
#define NT (KF / BK)   // 64
#define ASL 16384      // elements per K-tile slot (256*64)

#define SB0 __builtin_amdgcn_sched_barrier(0)
#define BARSYNC do { SB0; __builtin_amdgcn_s_barrier(); } while (0)
#define LGK(n) do { asm volatile("s_waitcnt lgkmcnt(" #n ")" ::: "memory"); SB0; } while (0)

__device__ __forceinline__ void read_a4(short8 (&afr)[2][2],
                                        const __hip_bfloat16* Asl,
                                        int row_base, int swz) {
#pragma unroll
  for (int mm = 0; mm < 2; ++mm)
#pragma unroll
    for (int ks = 0; ks < 2; ++ks)
      afr[mm][ks] = *(const short8*)(Asl + ks * 8192 + (row_base + mm * 16) * 32 + swz);
}

__device__ __forceinline__ void read_b8(short8 (&bfr)[4][2],
                                        const __hip_bfloat16* Bsl,
                                        int brow, int swz) {
#pragma unroll
  for (int nf = 0; nf < 4; ++nf)
#pragma unroll
    for (int ks = 0; ks < 2; ++ks)
      bfr[nf][ks] = *(const short8*)(Bsl + ks * 8192 + (brow + nf * 16) * 32 + swz);
}

template <int P>
__device__ __forceinline__ void mfma16(floatx4 (&acc)[8][4],
                                       const short8 (&afr)[2][2],
                                       const short8 (&bfr)[4][2]) {
#pragma unroll
  for (int ks = 0; ks < 2; ++ks)
#pragma unroll
    for (int mm = 0; mm < 2; ++mm)
#pragma unroll
      for (int nf = 0; nf < 4; ++nf)
        acc[P * 2 + mm][nf] = __builtin_amdgcn_mfma_f32_16x16x32_bf16(
            afr[mm][ks], bfr[nf][ks], acc[P * 2 + mm][nf], 0, 0, 0);
}

__global__ __launch_bounds__(512, 2) void gemm_xwt(
    const __hip_bfloat16* __restrict__ A,   // [M_TOK][KF]
    const __hip_bfloat16* __restrict__ B,   // [NF][KF]  (= Wb, row = n)
    float* __restrict__ C) {                // [M_TOK][NF]
  extern __shared__ __hip_bfloat16 lds[];
  __hip_bfloat16* As = lds;            // 2 slots x 16384 elems
  __hip_bfloat16* Bs = lds + 2 * ASL;  // 2 slots x 16384 elems
  const __hip_bfloat16* As0 = As;
  const __hip_bfloat16* As1 = As + ASL;
  const __hip_bfloat16* Bs0 = Bs;
  const __hip_bfloat16* Bs1 = Bs + ASL;

  const int t = threadIdx.x;       // 0..511
  const int lane = t & 63;
  const int wave = t >> 6;         // 0..7
  const int wm = wave >> 2;        // 0..1 : M half (128 rows)
  const int wn = wave & 3;         // 0..3 : N quarter (64 cols)
  const int frow = lane & 15;
  const int kq = lane >> 4;
  const int swz = ((kq + (frow >> 1)) & 3) * 8;   // swizzled k-elem offset

  // XCD-bijective block swizzle: 512 wgs, 8 XCDs, 64 contiguous work/XCD.
  const int bid = blockIdx.x;
  const int wk = (bid & 7) * 64 + (bid >> 3);
  const int bm = wk >> 4;   // 0..31
  const int bn = wk & 15;   // 0..15

  // staging: thread t covers within-panel row (t>>2)(+h*128), global chunk c
  const int c = ((t & 3) - ((t >> 3) & 3)) & 3;
  const __hip_bfloat16* a_src = A + (size_t)(bm * BM + (t >> 2)) * KF + c * 8;
  const __hip_bfloat16* b_src = B + (size_t)(bn * BN + (t >> 2)) * KF + c * 8;
  __hip_bfloat16* a_dst = As + t * 8;
  __hip_bfloat16* b_dst = Bs + t * 8;

#define STAGE_A(kt_, slot_, h_)                                                        \
  do {                                                                                 \
    const __hip_bfloat16* s_ = a_src + ((kt_) & (NT - 1)) * BK + (size_t)(h_) * 128 * KF; \
    __hip_bfloat16* d_ = a_dst + (slot_) * ASL + (h_) * 4096;                          \
    load_lds16(s_, d_);                /* ks=0 panel */                                \
    load_lds16(s_ + 32, d_ + 8192);    /* ks=1 panel */                                \
  } while (0)
#define STAGE_B(kt_, slot_, h_)                                                        \
  do {                                                                                 \
    const __hip_bfloat16* s_ = b_src + ((kt_) & (NT - 1)) * BK + (size_t)(h_) * 128 * KF; \
    __hip_bfloat16* d_ = b_dst + (slot_) * ASL + (h_) * 4096;                          \
    load_lds16(s_, d_);                                                                \
    load_lds16(s_ + 32, d_ + 8192);                                                    \
  } while (0)

  floatx4 acc[8][4] = {};
  short8 bE[4][2], bO[4][2];   // B frags, even/odd tile
  short8 aX[2][2], aY[2][2];   // A-quad ping-pong

  const int arow = wm * 128 + frow;
  const int brow = wn * 64 + frow;

  // prologue: A(0),B(0) must land; B(1) may fly.
  STAGE_A(0, 0, 0); STAGE_A(0, 0, 1);
  STAGE_B(0, 0, 0); STAGE_B(0, 0, 1);
  STAGE_B(1, 1, 0); STAGE_B(1, 1, 1);
  asm volatile("s_waitcnt vmcnt(4)" ::: "memory");
  __builtin_amdgcn_s_barrier();
  read_b8(bE, Bs0, brow, swz);              // 8 reads  (tile 0 B)
  read_a4(aX, As0, arow + 0 * 32, swz);     // 4 reads  (tile 0 Aq0) -> 12 out

  for (int kt = 0; kt < NT; kt += 2) {
    // ================= tile e = kt (slot 0) =================
    // ph0
    read_a4(aY, As0, arow + 1 * 32, swz);
    STAGE_A(kt + 1, 1, 0);
    BARSYNC; LGK(4);
    __builtin_amdgcn_s_setprio(1); mfma16<0>(acc, aX, bE); __builtin_amdgcn_s_setprio(0);
    BARSYNC;
    // ph1
    read_a4(aX, As0, arow + 2 * 32, swz);
    STAGE_A(kt + 1, 1, 1);
    BARSYNC; LGK(4);
    __builtin_amdgcn_s_setprio(1); mfma16<1>(acc, aY, bE); __builtin_amdgcn_s_setprio(0);
    BARSYNC;
    // ph2  (vmcnt(2): retire A(e+1),B(e+1); keep B(e+2)h0 flying)
    read_a4(aY, As0, arow + 3 * 32, swz);
    STAGE_B(kt + 2, 0, 0);
    BARSYNC; LGK(4);
    __builtin_amdgcn_s_setprio(1); mfma16<2>(acc, aX, bE); __builtin_amdgcn_s_setprio(0);
    SB0;
    asm volatile("s_waitcnt vmcnt(2)" ::: "memory");
    __builtin_amdgcn_s_barrier();
    // ph3  (pre-read next tile's subtile 0 from slot 1: landed above)
    read_b8(bO, Bs1, brow, swz);
    read_a4(aX, As1, arow + 0 * 32, swz);
    STAGE_B(kt + 2, 0, 1);
    BARSYNC; LGK(12);
    __builtin_amdgcn_s_setprio(1); mfma16<3>(acc, aY, bE); __builtin_amdgcn_s_setprio(0);
    BARSYNC;

    // ================= tile o = kt+1 (slot 1) =================
    // ph0
    read_a4(aY, As1, arow + 1 * 32, swz);
    STAGE_A(kt + 2, 0, 0);
    BARSYNC; LGK(4);
    __builtin_amdgcn_s_setprio(1); mfma16<0>(acc, aX, bO); __builtin_amdgcn_s_setprio(0);
    BARSYNC;
    // ph1
    read_a4(aX, As1, arow + 2 * 32, swz);
    STAGE_A(kt + 2, 0, 1);
    BARSYNC; LGK(4);
    __builtin_amdgcn_s_setprio(1); mfma16<1>(acc, aY, bO); __builtin_amdgcn_s_setprio(0);
    BARSYNC;
    // ph2
    read_a4(aY, As1, arow + 3 * 32, swz);
    STAGE_B(kt + 3, 1, 0);
    BARSYNC; LGK(4);
    __builtin_amdgcn_s_setprio(1); mfma16<2>(acc, aX, bO); __builtin_amdgcn_s_setprio(0);
    SB0;
    asm volatile("s_waitcnt vmcnt(2)" ::: "memory");
    __builtin_amdgcn_s_barrier();
    // ph3
    read_b8(bE, Bs0, brow, swz);
    read_a4(aX, As0, arow + 0 * 32, swz);
    STAGE_B(kt + 3, 1, 1);
    BARSYNC; LGK(12);
    __builtin_amdgcn_s_setprio(1); mfma16<3>(acc, aY, bO); __builtin_amdgcn_s_setprio(0);
    BARSYNC;
  }

#undef STAGE_A
#undef STAGE_B

  // epilogue: D mapping col(n)=lane&15, row(m)=(lane>>4)*4+reg  [m89-verified]
  const int col0 = bn * BN + wn * 64 + (lane & 15);
  const int row0 = bm * BM + wm * 128 + (lane >> 4) * 4;
#pragma unroll
  for (int mf = 0; mf < 8; ++mf)
#pragma unroll
    for (int nf = 0; nf < 4; ++nf)
#pragma unroll
      for (int r = 0; r < 4; ++r)
        C[(size_t)(row0 + mf * 16 + r) * NF + (col0 + nf * 16)] = acc[mf][nf][r];
}

extern "C" void kernel_launch(void* const* d_in, const int* in_sizes, int n_in,
                              void* d_out, int out_size, void* d_ws, size_t ws_size,
                              hipStream_t stream) {
  const float* x      = (const float*)d_in[0];  // [8192][4096]
  const float* weight = (const float*)d_in[1];  // [4096][4096]
  const float* P      = (const float*)d_in[2];  // [4096][64]
  const float* Lam    = (const float*)d_in[3];  // [64]
  const float* Q      = (const float*)d_in[4];  // [64][4096]
  const unsigned char* mask = (const unsigned char*)d_in[5];  // [64] bool8
  float* out = (float*)d_out;

  __hip_bfloat16* Xb = (__hip_bfloat16*)d_ws;                         // 64 MB
  __hip_bfloat16* Wb = (__hip_bfloat16*)((char*)d_ws + (size_t)M_TOK * KF * 2);  // 32 MB

  static int smem_set = 0;
  if (!smem_set) {
    hipFuncSetAttribute((const void*)gemm_xwt,
                        hipFuncAttributeMaxDynamicSharedMemorySize, 131072);
    smem_set = 1;
  }

  // 1) x -> bf16
  cast_f32_bf16<<<(M_TOK * KF) / (256 * 8), 256, 0, stream>>>(x, Xb);
  // 2) W_eff -> bf16 (rank update folded into the W cast pass)
  build_weff<<<dim3(KF / 64, NF / 64), 256, 0, stream>>>(weight, P, Lam, Q, mask, Wb);
  // 3) out = Xb @ Wb^T   (512 blocks = 32 bm x 16 bn, XCD-swizzled)
  gemm_xwt<<<dim3((M_TOK / BM) * (NF / BN)), 512, 131072, stream>>>(Xb, Wb, out);
}

// Round 5
// 516.959 us; speedup vs baseline: 1.0730x; 1.0286x over previous
//
#include <hip/hip_runtime.h>
#include <hip/hip_bf16.h>
#include <stdint.h>

// Problem constants (AdaLoRALinear): out = x @ (W + 2*(P*Lambda*mask)@Q)^T
// Pipeline:
//   1) prep_all : blocks [0,16384) x->Xb cast (verbatim round-4 cast body);
//                 blocks [16384,20480) build_weff (verbatim round-4 body,
//                 blockIdx remapped). Round-2 mega_prep block-split pattern.
//   2) gemm_xwt : out = Xb @ Wb^T. Round-4 loop with RE-TIMED STAGING:
//                 B(t+2) at ph0/ph1, A(t+2) at ph3, vmcnt(4) gate at ph2-end
//                 now only demands loads issued >=3 phases earlier.
#define M_TOK 8192   // batch tokens
#define NF    4096   // OUT_F
#define KF    4096   // IN_F
#define RANK  64

typedef __attribute__((ext_vector_type(8))) short short8;   // 8 x bf16 (4 VGPRs)
typedef __attribute__((ext_vector_type(4))) float floatx4;  // MFMA acc

typedef const uint32_t __attribute__((address_space(1)))* gp1_t;
typedef uint32_t __attribute__((address_space(3)))* lp3_t;

__device__ __forceinline__ void load_lds16(const void* g, void* l) {
  // async global->LDS, 16 B per lane; LDS dest must be uniform_base + lane*16
  __builtin_amdgcn_global_load_lds((gp1_t)g, (lp3_t)l, 16, 0, 0);
}

// ---- Kernel 1: prep_all ------------------------------------------------------
// blocks [0, CASTX_BLOCKS)          : Xb = bf16(x), 8 elems/thread
// blocks [CASTX_BLOCKS, +4096)      : Wb = bf16(W + 2*(P*lam*mask)@Q), 64x64 tile
#define CASTX_BLOCKS ((M_TOK * KF) / (256 * 8))   // 16384
__global__ __launch_bounds__(256) void prep_all(
    const float* __restrict__ x, const float* __restrict__ W,
    const float* __restrict__ P, const float* __restrict__ Lam,
    const float* __restrict__ Q, const unsigned char* __restrict__ mask,
    __hip_bfloat16* __restrict__ Xb, __hip_bfloat16* __restrict__ Wb) {
  __shared__ float lam[RANK];
  __shared__ float plT[RANK][68];  // [r][n_local], padded vs bank conflicts
  __shared__ float Qs[RANK][68];   // [r][k_local]

  const int bid = blockIdx.x;
  const int t = threadIdx.x;

  if (bid < CASTX_BLOCKS) {
    // ---- x -> bf16 (verbatim round-4 cast body) ----
    size_t i = ((size_t)bid * 256 + t) * 8;
    float4 a = *(const float4*)(x + i);
    float4 b = *(const float4*)(x + i + 4);
    union { __hip_bfloat16 h[8]; uint4 u; } pk;
    pk.h[0] = __float2bfloat16(a.x); pk.h[1] = __float2bfloat16(a.y);
    pk.h[2] = __float2bfloat16(a.z); pk.h[3] = __float2bfloat16(a.w);
    pk.h[4] = __float2bfloat16(b.x); pk.h[5] = __float2bfloat16(b.y);
    pk.h[6] = __float2bfloat16(b.z); pk.h[7] = __float2bfloat16(b.w);
    *(uint4*)(Xb + i) = pk.u;
    return;
  }

  // ---- build_weff (verbatim round-4 body; blockIdx remapped:
  //      idx = n*64 + k  ->  n0 = (idx>>6)*64, k0 = (idx&63)*64) ----
  const int idx = bid - CASTX_BLOCKS;
  const int n0 = (idx >> 6) * 64;
  const int k0 = (idx & 63) * 64;

  if (t < RANK) lam[t] = 2.0f * Lam[t] * (mask[t] ? 1.0f : 0.0f);
  __syncthreads();

  {
    const int nl = t & 63;
    const int rg = (t >> 6) * 16;
    const float* p = P + (size_t)(n0 + nl) * RANK + rg;
#pragma unroll
    for (int j = 0; j < 16; j += 4) {
      float4 v = *(const float4*)(p + j);
      plT[rg + j + 0][nl] = v.x * lam[rg + j + 0];
      plT[rg + j + 1][nl] = v.y * lam[rg + j + 1];
      plT[rg + j + 2][nl] = v.z * lam[rg + j + 2];
      plT[rg + j + 3][nl] = v.w * lam[rg + j + 3];
    }
    const int r = t >> 2;
    const int kc = (t & 3) * 16;
    const float* q = Q + (size_t)r * KF + k0 + kc;
#pragma unroll
    for (int j = 0; j < 16; j += 4) {
      float4 v = *(const float4*)(q + j);
      Qs[r][kc + j + 0] = v.x;
      Qs[r][kc + j + 1] = v.y;
      Qs[r][kc + j + 2] = v.z;
      Qs[r][kc + j + 3] = v.w;
    }
  }
  __syncthreads();

  const int tn4 = t >> 4;
  const int tk4 = t & 15;
  float accv[4][4];
#pragma unroll
  for (int i = 0; i < 4; i++) {
    float4 w = *(const float4*)(W + (size_t)(n0 + tn4 * 4 + i) * KF + k0 + tk4 * 4);
    accv[i][0] = w.x; accv[i][1] = w.y; accv[i][2] = w.z; accv[i][3] = w.w;
  }
#pragma unroll 8
  for (int r = 0; r < RANK; r++) {
    float4 p4 = *(const float4*)&plT[r][tn4 * 4];
    float4 q4 = *(const float4*)&Qs[r][tk4 * 4];
#define ROWFMA(i, pi)                                                  \
    accv[i][0] += (pi) * q4.x; accv[i][1] += (pi) * q4.y;              \
    accv[i][2] += (pi) * q4.z; accv[i][3] += (pi) * q4.w;
    ROWFMA(0, p4.x) ROWFMA(1, p4.y) ROWFMA(2, p4.z) ROWFMA(3, p4.w)
#undef ROWFMA
  }
#pragma unroll
  for (int i = 0; i < 4; i++) {
    union { __hip_bfloat16 h[4]; uint2 u; } pk;
    pk.h[0] = __float2bfloat16(accv[i][0]);
    pk.h[1] = __float2bfloat16(accv[i][1]);
    pk.h[2] = __float2bfloat16(accv[i][2]);
    pk.h[3] = __float2bfloat16(accv[i][3]);
    *(uint2*)(Wb + (size_t)(n0 + tn4 * 4 + i) * KF + k0 + tk4 * 4) = pk.u;
  }
}

// ---- Kernel 2: C[m][n] = sum_k A[m][k]*B[n][k]; A,B bf16 row-major, C fp32.
//
// 256x256 tile, BK=64, 512 threads (8 waves, 2Mx4N), per-wave 128x64 output.
// 4 phases/K-tile, register-subtile double-buffer with counted lgkm (round 2/4),
// RE-TIMED STAGING this round (deeper vmcnt pipeline, a la m201's 3-half-tile
// depth): per tile t: ph0/ph1 stage B(t+2) (B slot free since t's B-frags were
// pre-read to registers at tile t-1 ph3); ph2 stages nothing; ph3 stages A(t+2)
// AFTER LGK(12) retires the slot's last read. Single vmcnt(4) at ph2-end.
//
// VMEM ledger (steady, per tile; 2 loads per STAGE_* call):
//   start: 8 = {B(t+1) 4 (issued t-1 ph0/1), A(t+1) 4 (issued t-1 ph3)}
//   ph0 +2, ph1 +2 (B(t+2)) -> 12
//   ph2-end vmcnt(4): retires B(t+1)+A(t+1) [distances 5-6 and 3 phases],
//                     keeps B(t+2) flying -> 4
//   ph3 +4 (A(t+2)) -> 8 = next tile's start.  Never drains below 4.
//   Gate correctness: ph3 pre-reads A(t+1),B(t+1) from slot^1 -> landed ^.
// DS ledger (per tile, in-order retirement):
//   enter ph0: 12 outstanding (prev ph3 pre-reads: B 8 + Aq0 4)
//   ph0 +4 (Aq1) ->16, LGK(4) retires the 12 -> MFMA<0>(aX=q0, b)
//   ph1 +4 (Aq2) -> 8, LGK(4) retires Aq1   -> MFMA<1>(aY=q1, b)
//   ph2 +4 (Aq3) -> 8, LGK(4) retires Aq2   -> MFMA<2>(aX=q2, b)
//   ph3 +12     -> 16, LGK(12) retires Aq3  -> STAGE_A (slot's reads done)
//                                           -> MFMA<3>(aY=q3, b)
// WAR windows: every STAGE into a region follows (a) in-wave LGK retiring that
// region's reads, or (b) >=1 barrier + >=300cyc global-write latency vs <=120cyc
// DS-read completion (same hazard class as rounds 1/2/4, all passing).
// Wrap staging in last 2 tiles writes junk only into slots whose real reads
// completed; junk pre-reads at tile NT-1 ph3 are never consumed.
#define BM 256
#define BN 256
#define BK 64
#define NT (KF / BK)   // 64
#define ASL 16384      // elements per K-tile slot (256*64)

#define SB0 __builtin_amdgcn_sched_barrier(0)
#define BARSYNC do { SB0; __builtin_amdgcn_s_barrier(); } while (0)
#define LGK(n) do { asm volatile("s_waitcnt lgkmcnt(" #n ")" ::: "memory"); SB0; } while (0)

__device__ __forceinline__ void read_a4(short8 (&afr)[2][2],
                                        const __hip_bfloat16* Asl,
                                        int row_base, int swz) {
#pragma unroll
  for (int mm = 0; mm < 2; ++mm)
#pragma unroll
    for (int ks = 0; ks < 2; ++ks)
      afr[mm][ks] = *(const short8*)(Asl + ks * 8192 + (row_base + mm * 16) * 32 + swz);
}

__device__ __forceinline__ void read_b8(short8 (&bfr)[4][2],
                                        const __hip_bfloat16* Bsl,
                                        int brow, int swz) {
#pragma unroll
  for (int nf = 0; nf < 4; ++nf)
#pragma unroll
    for (int ks = 0; ks < 2; ++ks)
      bfr[nf][ks] = *(const short8*)(Bsl + ks * 8192 + (brow + nf * 16) * 32 + swz);
}

template <int P>
__device__ __forceinline__ void mfma16(floatx4 (&acc)[8][4],
                                       const short8 (&afr)[2][2],
                                       const short8 (&bfr)[4][2]) {
#pragma unroll
  for (int ks = 0; ks < 2; ++ks)
#pragma unroll
    for (int mm = 0; mm < 2; ++mm)
#pragma unroll
      for (int nf = 0; nf < 4; ++nf)
        acc[P * 2 + mm][nf] = __builtin_amdgcn_mfma_f32_16x16x32_bf16(
            afr[mm][ks], bfr[nf][ks], acc[P * 2 + mm][nf], 0, 0, 0);
}

__global__ __launch_bounds__(512, 2) void gemm_xwt(
    const __hip_bfloat16* __restrict__ A,   // [M_TOK][KF]
    const __hip_bfloat16* __restrict__ B,   // [NF][KF]  (= Wb, row = n)
    float* __restrict__ C) {                // [M_TOK][NF]
  extern __shared__ __hip_bfloat16 lds[];
  __hip_bfloat16* As = lds;            // 2 slots x 16384 elems
  __hip_bfloat16* Bs = lds + 2 * ASL;  // 2 slots x 16384 elems
  const __hip_bfloat16* As0 = As;
  const __hip_bfloat16* As1 = As + ASL;
  const __hip_bfloat16* Bs0 = Bs;
  const __hip_bfloat16* Bs1 = Bs + ASL;

  const int t = threadIdx.x;       // 0..511
  const int lane = t & 63;
  const int wave = t >> 6;         // 0..7
  const int wm = wave >> 2;        // 0..1 : M half (128 rows)
  const int wn = wave & 3;         // 0..3 : N quarter (64 cols)
  const int frow = lane & 15;
  const int kq = lane >> 4;
  const int swz = ((kq + (frow >> 1)) & 3) * 8;   // swizzled k-elem offset

  // XCD-bijective block swizzle: 512 wgs, 8 XCDs, 64 contiguous work/XCD.
  const int bid = blockIdx.x;
  const int wk = (bid & 7) * 64 + (bid >> 3);
  const int bm = wk >> 4;   // 0..31
  const int bn = wk & 15;   // 0..15

  // staging: thread t covers within-panel row (t>>2)(+h*128), global chunk c
  const int c = ((t & 3) - ((t >> 3) & 3)) & 3;
  const __hip_bfloat16* a_src = A + (size_t)(bm * BM + (t >> 2)) * KF + c * 8;
  const __hip_bfloat16* b_src = B + (size_t)(bn * BN + (t >> 2)) * KF + c * 8;
  __hip_bfloat16* a_dst = As + t * 8;
  __hip_bfloat16* b_dst = Bs + t * 8;

#define STAGE_A(kt_, slot_, h_)                                                        \
  do {                                                                                 \
    const __hip_bfloat16* s_ = a_src + ((kt_) & (NT - 1)) * BK + (size_t)(h_) * 128 * KF; \
    __hip_bfloat16* d_ = a_dst + (slot_) * ASL + (h_) * 4096;                          \
    load_lds16(s_, d_);                /* ks=0 panel */                                \
    load_lds16(s_ + 32, d_ + 8192);    /* ks=1 panel */                                \
  } while (0)
#define STAGE_B(kt_, slot_, h_)                                                        \
  do {                                                                                 \
    const __hip_bfloat16* s_ = b_src + ((kt_) & (NT - 1)) * BK + (size_t)(h_) * 128 * KF; \
    __hip_bfloat16* d_ = b_dst + (slot_) * ASL + (h_) * 4096;                          \
    load_lds16(s_, d_);                                                                \
    load_lds16(s_ + 32, d_ + 8192);                                                    \
  } while (0)

  floatx4 acc[8][4] = {};
  short8 bE[4][2], bO[4][2];   // B frags, even/odd tile
  short8 aX[2][2], aY[2][2];   // A-quad ping-pong

  const int arow = wm * 128 + frow;
  const int brow = wn * 64 + frow;

  // prologue: A(0),B(0) must land; A(1),B(1) may fly (gated at tile-0 ph2).
  STAGE_A(0, 0, 0); STAGE_A(0, 0, 1);
  STAGE_B(0, 0, 0); STAGE_B(0, 0, 1);
  STAGE_A(1, 1, 0); STAGE_A(1, 1, 1);
  STAGE_B(1, 1, 0); STAGE_B(1, 1, 1);
  asm volatile("s_waitcnt vmcnt(8)" ::: "memory");   // A(0),B(0) landed
  __builtin_amdgcn_s_barrier();
  read_b8(bE, Bs0, brow, swz);              // 8 reads  (tile 0 B)
  read_a4(aX, As0, arow + 0 * 32, swz);     // 4 reads  (tile 0 Aq0) -> 12 out

  for (int kt = 0; kt < NT; kt += 2) {
    // ================= tile e = kt (slot 0) =================
    // ph0
    read_a4(aY, As0, arow + 1 * 32, swz);
    STAGE_B(kt + 2, 0, 0);
    BARSYNC; LGK(4);
    __builtin_amdgcn_s_setprio(1); mfma16<0>(acc, aX, bE); __builtin_amdgcn_s_setprio(0);
    BARSYNC;
    // ph1
    read_a4(aX, As0, arow + 2 * 32, swz);
    STAGE_B(kt + 2, 0, 1);
    BARSYNC; LGK(4);
    __builtin_amdgcn_s_setprio(1); mfma16<1>(acc, aY, bE); __builtin_amdgcn_s_setprio(0);
    BARSYNC;
    // ph2  (no staging; vmcnt(4) retires A(e+1),B(e+1), keeps B(e+2) flying)
    read_a4(aY, As0, arow + 3 * 32, swz);
    BARSYNC; LGK(4);
    __builtin_amdgcn_s_setprio(1); mfma16<2>(acc, aX, bE); __builtin_amdgcn_s_setprio(0);
    SB0;
    asm volatile("s_waitcnt vmcnt(4)" ::: "memory");
    __builtin_amdgcn_s_barrier();
    // ph3  (pre-read next tile's subtile 0; then stage A(e+2) into the slot
    //       whose last read LGK(12) just retired)
    read_b8(bO, Bs1, brow, swz);
    read_a4(aX, As1, arow + 0 * 32, swz);
    BARSYNC; LGK(12);
    STAGE_A(kt + 2, 0, 0);
    STAGE_A(kt + 2, 0, 1);
    SB0;
    __builtin_amdgcn_s_setprio(1); mfma16<3>(acc, aY, bE); __builtin_amdgcn_s_setprio(0);
    BARSYNC;

    // ================= tile o = kt+1 (slot 1) =================
    // ph0
    read_a4(aY, As1, arow + 1 * 32, swz);
    STAGE_B(kt + 3, 1, 0);
    BARSYNC; LGK(4);
    __builtin_amdgcn_s_setprio(1); mfma16<0>(acc, aX, bO); __builtin_amdgcn_s_setprio(0);
    BARSYNC;
    // ph1
    read_a4(aX, As1, arow + 2 * 32, swz);
    STAGE_B(kt + 3, 1, 1);
    BARSYNC; LGK(4);
    __builtin_amdgcn_s_setprio(1); mfma16<1>(acc, aY, bO); __builtin_amdgcn_s_setprio(0);
    BARSYNC;
    // ph2
    read_a4(aY, As1, arow + 3 * 32, swz);
    BARSYNC; LGK(4);
    __builtin_amdgcn_s_setprio(1); mfma16<2>(acc, aX, bO); __builtin_amdgcn_s_setprio(0);
    SB0;
    asm volatile("s_waitcnt vmcnt(4)" ::: "memory");
    __builtin_amdgcn_s_barrier();
    // ph3
    read_b8(bE, Bs0, brow, swz);
    read_a4(aX, As0, arow + 0 * 32, swz);
    BARSYNC; LGK(12);
    STAGE_A(kt + 3, 1, 0);
    STAGE_A(kt + 3, 1, 1);
    SB0;
    __builtin_amdgcn_s_setprio(1); mfma16<3>(acc, aY, bO); __builtin_amdgcn_s_setprio(0);
    BARSYNC;
  }

#undef STAGE_A
#undef STAGE_B

  // epilogue: D mapping col(n)=lane&15, row(m)=(lane>>4)*4+reg  [m89-verified]
  const int col0 = bn * BN + wn * 64 + (lane & 15);
  const int row0 = bm * BM + wm * 128 + (lane >> 4) * 4;
#pragma unroll
  for (int mf = 0; mf < 8; ++mf)
#pragma unroll
    for (int nf = 0; nf < 4; ++nf)
#pragma unroll
      for (int r = 0; r < 4; ++r)
        C[(size_t)(row0 + mf * 16 + r) * NF + (col0 + nf * 16)] = acc[mf][nf][r];
}

extern "C" void kernel_launch(void* const* d_in, const int* in_sizes, int n_in,
                              void* d_out, int out_size, void* d_ws, size_t ws_size,
                              hipStream_t stream) {
  const float* x      = (const float*)d_in[0];  // [8192][4096]
  const float* weight = (const float*)d_in[1];  // [4096][4096]
  const float* P      = (const float*)d_in[2];  // [4096][64]
  const float* Lam    = (const float*)d_in[3];  // [64]
  const float* Q      = (const float*)d_in[4];  // [64][4096]
  const unsigned char* mask = (const unsigned char*)d_in[5];  // [64] bool8
  float* out = (float*)d_out;

  __hip_bfloat16* Xb = (__hip_bfloat16*)d_ws;                         // 64 MB
  __hip_bfloat16* Wb = (__hip_bfloat16*)((char*)d_ws + (size_t)M_TOK * KF * 2);  // 32 MB

  static int smem_set = 0;
  if (!smem_set) {
    hipFuncSetAttribute((const void*)gemm_xwt,
                        hipFuncAttributeMaxDynamicSharedMemorySize, 131072);
    smem_set = 1;
  }

  // 1) Xb cast + W_eff build (one launch, block-range split)
  prep_all<<<CASTX_BLOCKS + (NF / 64) * (KF / 64), 256, 0, stream>>>(
      x, weight, P, Lam, Q, mask, Xb, Wb);
  // 2) out = Xb @ Wb^T   (512 blocks = 32 bm x 16 bn, XCD-swizzled)
  gemm_xwt<<<dim3((M_TOK / BM) * (NF / BN)), 512, 131072, stream>>>(Xb, Wb, out);
}